// Round 6
// baseline (320.121 us; speedup 1.0000x reference)
//
#include <hip/hip_runtime.h>
#include <math.h>

#define IMG_H 512
#define IMG_W 512
#define NIMG 32
#define W_T 256
#define H_T 64
#define RB 13            // staged rows per batch
#define NB 8             // batches: rows m=0..103 staged, m<=97 used
#define SQ 74            // float4 per staged row (gx = x0-20 .. x0+275)
#define SW 296           // floats per staged row (= SQ*4, keeps LDS flat-contiguous)
#define TQ 72            // float4 per win5 row
#define TW 288           // floats per win5 row (centers 0..287; need <=285)
#define NSLOT  (RB * SQ) // 962
#define NSLOT5 (RB * TQ) // 936

// Fused dark-channel loss with register-prefetch double buffering:
// loads for batch bt+1 are issued before win5+gather of batch bt, so VMEM
// stays in flight across the barrier-separated LDS phases.
__global__ __launch_bounds__(256, 2) void dc_fused(const float* __restrict__ img,
                                                   float* __restrict__ out) {
    __shared__ float rowbuf[RB][SW];
    __shared__ float tmp5[RB][TW];
    __shared__ float wsum[4];
    const int b = blockIdx.x;             // n*16 + yt*2 + xt
    const int xt = b & 1;
    const int yt = (b >> 1) & 7;
    const int n = b >> 4;
    const int x0 = xt * W_T;
    const int y0 = yt * H_T;
    const int tid = (int)threadIdx.x;
    const float4* img4 = (const float4*)img + (size_t)n * 196608;  // n*3*H*W/4

    // ---- loop-invariant slot decompositions (computed once) ----
    int sj[4], sq4[4], sqo[4]; bool sact[4], sokx[4];
    #pragma unroll
    for (int ii = 0; ii < 4; ++ii) {
        int p = tid + ii * 256;
        sact[ii] = p < NSLOT;
        if (p >= NSLOT) p = NSLOT - 1;
        const int j = p / SQ, q = p - j * SQ;
        sj[ii] = j; sq4[ii] = q << 2;
        const int gx0 = x0 - 20 + (q << 2);
        const int gxc = min(max(gx0, 0), IMG_W - 4);   // float4 fully in or out
        sokx[ii] = (gx0 == gxc);
        sqo[ii] = gxc >> 2;
    }
    int wj[4], wq4[4]; bool wact[4];
    #pragma unroll
    for (int ii = 0; ii < 4; ++ii) {
        int p = tid + ii * 256;
        wact[ii] = p < NSLOT5;
        if (p >= NSLOT5) p = NSLOT5 - 1;
        const int j = p / TQ, q = p - j * TQ;
        wj[ii] = j; wq4[ii] = q << 2;
    }

    float A[H_T];
    float r0 = 0.f, r1 = 0.f, r2 = 0.f, r3 = 0.f, r4 = 0.f;
    float s = 0.f;
    float4 c0[4], c1[4], c2[4];
    bool oky[4];

    // ---- issue batch 0 ----
    #pragma unroll
    for (int ii = 0; ii < 4; ++ii) {
        const int gy = y0 - 17 + sj[ii];
        const int gyc = min(max(gy, 0), IMG_H - 1);
        oky[ii] = (gy == gyc) && sokx[ii];
        const float4* p0 = img4 + (gyc << 7) + sqo[ii];
        c0[ii] = p0[0]; c1[ii] = p0[65536]; c2[ii] = p0[131072];
    }

    #pragma unroll
    for (int bt = 0; bt < NB; ++bt) {
        // ---- consume prefetched regs -> cmax -> LDS ----
        #pragma unroll
        for (int ii = 0; ii < 4; ++ii) {
            float4 f;
            f.x = oky[ii] ? 1.0f - fminf(c0[ii].x, fminf(c1[ii].x, c2[ii].x)) : -INFINITY;
            f.y = oky[ii] ? 1.0f - fminf(c0[ii].y, fminf(c1[ii].y, c2[ii].y)) : -INFINITY;
            f.z = oky[ii] ? 1.0f - fminf(c0[ii].z, fminf(c1[ii].z, c2[ii].z)) : -INFINITY;
            f.w = oky[ii] ? 1.0f - fminf(c0[ii].w, fminf(c1[ii].w, c2[ii].w)) : -INFINITY;
            if (sact[ii]) *(float4*)&rowbuf[sj[ii]][sq4[ii]] = f;
        }
        __syncthreads();                                   // B1
        // ---- issue batch bt+1 (in flight during win5 + gather) ----
        if (bt + 1 < NB) {
            #pragma unroll
            for (int ii = 0; ii < 4; ++ii) {
                const int gy = y0 - 17 + (bt + 1) * RB + sj[ii];
                const int gyc = min(max(gy, 0), IMG_H - 1);
                oky[ii] = (gy == gyc) && sokx[ii];
                const float4* p0 = img4 + (gyc << 7) + sqo[ii];
                c0[ii] = p0[0]; c1[ii] = p0[65536]; c2[ii] = p0[131072];
            }
        }
        // ---- horizontal win5: tmp5[j][c] = max(rowbuf[j][c+3..c+7]) ----
        #pragma unroll
        for (int ii = 0; ii < 4; ++ii) {
            if (wact[ii]) {
                const float* rp = &rowbuf[wj[ii]][wq4[ii]];
                const float4 a  = *(const float4*)(rp);
                const float4 bq = *(const float4*)(rp + 4);
                const float4 cq = *(const float4*)(rp + 8);
                const float sb1 = fmaxf(bq.y, fmaxf(bq.z, bq.w));
                const float m4b = fmaxf(bq.x, sb1);
                const float sb2 = fmaxf(bq.z, bq.w);
                const float pc2 = fmaxf(cq.x, cq.y);
                float4 t;
                t.x = fmaxf(a.w, m4b);
                t.y = fmaxf(m4b, cq.x);
                t.z = fmaxf(sb1, pc2);
                t.w = fmaxf(sb2, fmaxf(pc2, cq.z));
                *(float4*)&tmp5[wj[ii]][wq4[ii]] = t;
            }
        }
        __syncthreads();                                   // B2
        // ---- horizontal win35 gather + vertical 5+7 register pipeline ----
        #pragma unroll
        for (int j = 0; j < RB; ++j) {
            const int m = bt * RB + j;                     // compile-time
            if (m <= 97) {
                float h = tmp5[j][tid];
                #pragma unroll
                for (int k = 1; k < 7; ++k) h = fmaxf(h, tmp5[j][tid + 5 * k]);
                r0 = r1; r1 = r2; r2 = r3; r3 = r4; r4 = h;
                if (m >= 4) {
                    const int mg = m - 4;                  // 0..93
                    const float g = fmaxf(fmaxf(fmaxf(r0, r1), fmaxf(r2, r3)), r4);
                    #pragma unroll
                    for (int k = 0; k < 7; ++k) {
                        const int i = mg - 5 * k;
                        if (i >= 0 && i < H_T) {
                            if (i == mg) A[i] = g;         // first touch (k==0)
                            else A[i] = fmaxf(A[i], g);
                        }
                    }
                    if (mg >= 30) s += fabsf(A[mg - 30]);
                }
            }
        }
    }

    // ---- block reduction + one atomic ----
    #pragma unroll
    for (int off = 32; off > 0; off >>= 1) s += __shfl_down(s, off);
    const int lane = tid & 63, wv = tid >> 6;
    if (lane == 0) wsum[wv] = s;
    __syncthreads();
    if (tid == 0) {
        float t = wsum[0] + wsum[1] + wsum[2] + wsum[3];
        atomicAdd(out, t * (1.0f / ((float)NIMG * IMG_H * IMG_W)));
    }
}

extern "C" void kernel_launch(void* const* d_in, const int* in_sizes, int n_in,
                              void* d_out, int out_size, void* d_ws, size_t ws_size,
                              hipStream_t stream) {
    const float* img = (const float*)d_in[0];
    float* out = (float*)d_out;
    (void)d_ws; (void)ws_size;

    hipMemsetAsync(d_out, 0, sizeof(float), stream);
    dc_fused<<<NIMG * (IMG_H / H_T) * (IMG_W / W_T), 256, 0, stream>>>(img, out);
}

// Round 7
// 182.394 us; speedup vs baseline: 1.7551x; 1.7551x over previous
//
#include <hip/hip_runtime.h>
#include <math.h>

#define IMG_H 512
#define IMG_W 512
#define NIMG 32
#define AR 4            // rows per block, pass A
#define SW 552          // rowbuf floats/row: rowbuf[i] = cmax(clamp(i-20)), i in [0,552)
#define SQ 138          // float4 per staged row
#define TW 544          // tmp5 floats/row: tmp5[i] = win5 over rowbuf[i+3..i+7]
#define TQ 136          // float4 per win5 row
#define YC 16           // output rows per block, pass B

// Replicate-clamp == -inf padding for max pooling: every clamped duplicate is a
// copy of a column/row that is inside the clipped window of every output that
// reads it (edge outputs' windows always contain the edge texel). So no masks.

// ---------------- Pass A: cmax + horizontal win35 -> rowmax (ws) ----------------
__global__ __launch_bounds__(256) void dc_rowmax(const float* __restrict__ img,
                                                 float* __restrict__ rowmax) {
    __shared__ float rowbuf[AR][SW];
    __shared__ float tmp5[AR][TW];
    const int b = blockIdx.x;             // n*128 + ytile
    const int n = b >> 7;
    const int y0 = (b & 127) * AR;
    const int tid = (int)threadIdx.x;
    const float4* img4 = (const float4*)img + (size_t)n * 196608;   // n*3*H*W/4

    // stage: unconditional clamped float4 loads, cmax = 1 - min3
    #pragma unroll
    for (int ii = 0; ii < 3; ++ii) {
        const int p = tid + ii * 256;
        if (p < AR * SQ) {
            const int r = p / SQ, q = p - r * SQ;
            const int gx0 = (q << 2) - 20;
            const int gxc = min(max(gx0, 0), IMG_W - 4);   // float4 stays in-image
            const float4* p0 = img4 + (((size_t)(y0 + r)) << 7) + (gxc >> 2);
            const float4 a  = p0[0];
            const float4 c1 = p0[65536];
            const float4 c2 = p0[131072];
            float4 f;
            f.x = 1.0f - fminf(a.x, fminf(c1.x, c2.x));
            f.y = 1.0f - fminf(a.y, fminf(c1.y, c2.y));
            f.z = 1.0f - fminf(a.z, fminf(c1.z, c2.z));
            f.w = 1.0f - fminf(a.w, fminf(c1.w, c2.w));
            *(float4*)&rowbuf[r][q << 2] = f;
        }
    }
    __syncthreads();
    // win5: tmp5[r][i] = max(rowbuf[r][i+3 .. i+7]), 4 slots from 3 b128 reads
    #pragma unroll
    for (int ii = 0; ii < 3; ++ii) {
        const int p = tid + ii * 256;
        if (p < AR * TQ) {
            const int r = p / TQ, q = p - r * TQ;
            const float* rp = &rowbuf[r][q << 2];
            const float4 a  = *(const float4*)(rp);
            const float4 bq = *(const float4*)(rp + 4);
            const float4 cq = *(const float4*)(rp + 8);
            const float sb1 = fmaxf(bq.y, fmaxf(bq.z, bq.w));
            const float m4b = fmaxf(bq.x, sb1);
            const float sb2 = fmaxf(bq.z, bq.w);
            const float pc2 = fmaxf(cq.x, cq.y);
            float4 t;
            t.x = fmaxf(a.w, m4b);
            t.y = fmaxf(m4b, cq.x);
            t.z = fmaxf(sb1, pc2);
            t.w = fmaxf(sb2, fmaxf(pc2, cq.z));
            *(float4*)&tmp5[r][q << 2] = t;
        }
    }
    __syncthreads();
    // win35: out[x] = max_k tmp5[x + 5k], k=0..6
    float* orow = rowmax + ((size_t)n * IMG_H + y0) * IMG_W;
    #pragma unroll
    for (int ii = 0; ii < 8; ++ii) {
        const int idx = tid + ii * 256;          // 0 .. 2047
        const int r = idx >> 9, x = idx & 511;
        float m = tmp5[r][x];
        #pragma unroll
        for (int k = 1; k < 7; ++k) m = fmaxf(m, tmp5[r][x + 5 * k]);
        orow[(size_t)r * IMG_W + x] = m;
    }
}

// ------- Pass B: vertical win35 (5+7 register pipeline) + mean reduction -------
__global__ __launch_bounds__(256) void dc_colmax(const float* __restrict__ rowmax,
                                                 float* __restrict__ out) {
    __shared__ float wsum[4];
    const int b = blockIdx.x;             // n*64 + yt*2 + xt
    const int xt = b & 1;
    const int yt = (b >> 1) & 31;
    const int n = b >> 6;
    const int x = xt * 256 + (int)threadIdx.x;
    const int y0 = yt * YC;
    const float* col = rowmax + (size_t)n * IMG_H * IMG_W + x;

    float A[YC];
    float r0 = 0.f, r1 = 0.f, r2 = 0.f, r3 = 0.f, r4 = 0.f;
    float s = 0.f;
    #pragma unroll
    for (int m = 0; m < YC + 34; ++m) {
        const int gy = min(max(y0 - 17 + m, 0), IMG_H - 1);  // replicate == -inf pad
        const float v = col[(size_t)gy << 9];
        r0 = r1; r1 = r2; r2 = r3; r3 = r4; r4 = v;
        if (m >= 4) {
            const int mg = m - 4;                 // compile-time after unroll
            const float g = fmaxf(fmaxf(fmaxf(r0, r1), fmaxf(r2, r3)), r4);
            #pragma unroll
            for (int k = 0; k < 7; ++k) {
                const int i = mg - 5 * k;
                if (i >= 0 && i < YC) {
                    if (i == mg) A[i] = g;        // first touch (k==0)
                    else A[i] = fmaxf(A[i], g);
                }
            }
            if (mg >= 30) s += fabsf(A[mg - 30]);
        }
    }
    #pragma unroll
    for (int off = 32; off > 0; off >>= 1) s += __shfl_down(s, off);
    const int lane = (int)threadIdx.x & 63, wv = (int)threadIdx.x >> 6;
    if (lane == 0) wsum[wv] = s;
    __syncthreads();
    if (threadIdx.x == 0) {
        float t = wsum[0] + wsum[1] + wsum[2] + wsum[3];
        atomicAdd(out, t * (1.0f / ((float)NIMG * IMG_H * IMG_W)));
    }
}

extern "C" void kernel_launch(void* const* d_in, const int* in_sizes, int n_in,
                              void* d_out, int out_size, void* d_ws, size_t ws_size,
                              hipStream_t stream) {
    const float* img = (const float*)d_in[0];
    float* out = (float*)d_out;
    float* rowmax = (float*)d_ws;     // 33.5 MB scratch

    hipMemsetAsync(d_out, 0, sizeof(float), stream);
    dc_rowmax<<<NIMG * (IMG_H / AR), 256, 0, stream>>>(img, rowmax);
    dc_colmax<<<NIMG * (IMG_H / YC) * 2, 256, 0, stream>>>(rowmax, out);
}